// Round 22
// baseline (1304.968 us; speedup 1.0000x reference)
//
#include <hip/hip_runtime.h>
#include <hip/hip_bf16.h>
#include <stdint.h>

#define M_TOTAL 8192      // BATCH*SEQ
#define N_TOTAL 16384     // OUT_FEATURES
#define K_TOTAL 4096      // IN_FEATURES (== BLOCKSIZE -> absmax is per output row)

#define BM 256
#define BN 128
#define BK 32
#define NKT (K_TOTAL / BK)   // 128 K-tiles

using f32x4  = __attribute__((ext_vector_type(4))) float;
using bf16x8 = __attribute__((ext_vector_type(8))) short;

#define UNROLL _Pragma("unroll")

__device__ __forceinline__ unsigned short f2bf(float f) {
    union { float f; unsigned u; } v; v.f = f;
    unsigned r = v.u + 0x7fffu + ((v.u >> 16) & 1u);   // RNE
    return (unsigned short)(r >> 16);
}

__device__ __forceinline__ void gload_lds16(const void* g, void* l) {
    __builtin_amdgcn_global_load_lds(
        (const __attribute__((address_space(1))) unsigned int*)g,
        (__attribute__((address_space(3))) unsigned int*)l,
        16, 0, 0);
}

// ---------------- dequant W: wb[o*K+i] = bf16(code[q[o*K+i]] * absmax[o]) ----------
__global__ void dequant_w_kernel(const int* __restrict__ q,
                                 const float* __restrict__ am,
                                 const float* __restrict__ code,
                                 unsigned short* __restrict__ wb) {
    __shared__ float lc[256];
    if (threadIdx.x < 256) lc[threadIdx.x] = code[threadIdx.x];
    __syncthreads();
    const int total = (N_TOTAL / 4) * K_TOTAL;   // 16,777,216 int4 groups
    const int stride = gridDim.x * blockDim.x;
    for (int i = blockIdx.x * blockDim.x + threadIdx.x; i < total; i += stride) {
        int4 v = reinterpret_cast<const int4*>(q)[i];
        float a = am[i >> 10];                   // one quant block == one weight row
        ushort4 o;
        o.x = f2bf(lc[v.x & 255] * a);
        o.y = f2bf(lc[v.y & 255] * a);
        o.z = f2bf(lc[v.z & 255] * a);
        o.w = f2bf(lc[v.w & 255] * a);
        reinterpret_cast<ushort4*>(wb)[i] = o;
    }
}

// ---------------- convert x fp32 -> bf16 ----------------
__global__ void cvt_x_kernel(const float* __restrict__ x,
                             unsigned short* __restrict__ xb) {
    const int total = (M_TOTAL * K_TOTAL) / 4;
    const int stride = gridDim.x * blockDim.x;
    for (int i = blockIdx.x * blockDim.x + threadIdx.x; i < total; i += stride) {
        float4 v = reinterpret_cast<const float4*>(x)[i];
        ushort4 o;
        o.x = f2bf(v.x); o.y = f2bf(v.y); o.z = f2bf(v.z); o.w = f2bf(v.w);
        reinterpret_cast<ushort4*>(xb)[i] = o;
    }
}

// ---- GEMM 256x128x32: 4-wave blocks, 2 blocks/CU (two independent barrier
// ---- domains per CU -> cross-block TLP covers each other's drains).
// Per-wave registers ~224 (128 AGPR acc + ~96 VGPR) -> exactly 2 waves/SIMD;
// with 4-wave blocks those 2 waves belong to DIFFERENT blocks.
// LDS layout per buffer (r13-verified, 0 conflicts): [rows][32] bf16, 4 chunks
// of 8 elems/row; LDS(row, d) holds global chunk d ^ ((row>>1)&3).
//  - staging: linear dest (base + lane*16), pre-swizzled per-lane global source
//  - frag read: phys chunk = (lane>>4) ^ ((row>>1)&3)
__global__ __launch_bounds__(256, 2) void gemm_tb_kernel(
        const unsigned short* __restrict__ A,   // [M][K] bf16
        const unsigned short* __restrict__ B,   // [N][K] bf16
        const float* __restrict__ bias,         // [N]
        float* __restrict__ C) {                // [M][N] f32
    __shared__ __align__(16) unsigned short sA[2][BM * BK];   // 2 x 16 KiB
    __shared__ __align__(16) unsigned short sB[2][BN * BK];   // 2 x  8 KiB

    // XCD swizzle (nwg = 4096, % 8 == 0 -> bijective)
    const int nwg = gridDim.x;
    const int bid = blockIdx.x;
    const int wg  = (bid & 7) * (nwg >> 3) + (bid >> 3);
    const int nbn = N_TOTAL / BN;            // 128
    const int brow = (wg / nbn) * BM;
    const int bcol = (wg % nbn) * BN;

    const int tid  = threadIdx.x;
    const int wid  = tid >> 6;               // 0..3
    const int lane = tid & 63;
    const int wm   = wid >> 1;               // 0..1  (M-waves, 128 rows each)
    const int wn   = wid & 1;                // 0..1  (N-waves,  64 cols each)

    // staging: group g = 16 rows (1 KiB). A: 16 groups, B: 8 groups.
    // wave wid owns A groups {wid*4..wid*4+3}, B groups {wid*2, wid*2+1}.
    // lane -> local row = lane>>2, dest chunk = lane&3,
    // source chunk = (lane&3) ^ ((lane>>3)&3)   (pre-swizzled for linear dest)
    const int sro = lane >> 2;                               // local row 0..15
    const int sco = ((lane & 3) ^ ((lane >> 3) & 3)) * 8;    // pre-swizzled col
    const unsigned short* Asrc = A + (long long)brow * K_TOTAL + sco;
    const unsigned short* Bsrc = B + (long long)bcol * K_TOTAL + sco;

    auto stage = [&](int kt, int b) {   // 6 issues/wave (4 A + 2 B)
        UNROLL for (int i = 0; i < 4; ++i) {
            const int g = wid * 4 + i;
            gload_lds16(Asrc + (long long)(g * 16 + sro) * K_TOTAL + kt * BK,
                        &sA[b][g * 512]);
        }
        UNROLL for (int i = 0; i < 2; ++i) {
            const int g = wid * 2 + i;
            gload_lds16(Bsrc + (long long)(g * 16 + sro) * K_TOTAL + kt * BK,
                        &sB[b][g * 512]);
        }
    };

    const int l15 = lane & 15;
    const int rch = lane >> 4;               // logical k-chunk 0..3

    f32x4 acc[8][4];                         // 128x64 per wave = 128 f32 (AGPR)
    UNROLL for (int mf = 0; mf < 8; ++mf)
        UNROLL for (int nf = 0; nf < 4; ++nf)
            acc[mf][nf] = (f32x4){0.f, 0.f, 0.f, 0.f};

    // prologue: tile0 -> buf0
    stage(0, 0);
    __syncthreads();

    // main loop: one __syncthreads per K-tile; the co-resident block's waves
    // (independent barrier domain) cover this block's drain + barrier stalls.
    for (int t = 0; t < NKT; ++t) {
        const int p = t & 1;
        if (t + 1 < NKT) stage(t + 1, p ^ 1);

        bf16x8 a_r[8], b_r[4];
        UNROLL for (int mf = 0; mf < 8; ++mf) {
            const int row = wm * 128 + mf * 16 + l15;
            a_r[mf] = *reinterpret_cast<const bf16x8*>(
                &sA[p][row * BK + ((rch ^ ((row >> 1) & 3)) * 8)]);
        }
        UNROLL for (int nf = 0; nf < 4; ++nf) {
            const int row = wn * 64 + nf * 16 + l15;
            b_r[nf] = *reinterpret_cast<const bf16x8*>(
                &sB[p][row * BK + ((rch ^ ((row >> 1) & 3)) * 8)]);
        }

        __builtin_amdgcn_s_setprio(1);
        UNROLL for (int mf = 0; mf < 8; ++mf)
            UNROLL for (int nf = 0; nf < 4; ++nf)
                acc[mf][nf] = __builtin_amdgcn_mfma_f32_16x16x32_bf16(
                    a_r[mf], b_r[nf], acc[mf][nf], 0, 0, 0);
        __builtin_amdgcn_s_setprio(0);

        __syncthreads();   // full drain + barrier; other block covers the stall
    }

    // ---- epilogue: C/D layout col = lane&15, row = (lane>>4)*4 + r ----
    const int crow0 = (lane >> 4) * 4;
    const int ccol  = lane & 15;
    UNROLL for (int mf = 0; mf < 8; ++mf) {
        const long long row0 = (long long)brow + wm * 128 + mf * 16 + crow0;
        UNROLL for (int nf = 0; nf < 4; ++nf) {
            const int col = bcol + wn * 64 + nf * 16 + ccol;
            const float bv = bias[col];
            UNROLL for (int r = 0; r < 4; ++r)
                C[(row0 + r) * N_TOTAL + col] = acc[mf][nf][r] + bv;
        }
    }
}

extern "C" void kernel_launch(void* const* d_in, const int* in_sizes, int n_in,
                              void* d_out, int out_size, void* d_ws, size_t ws_size,
                              hipStream_t stream) {
    const float* x      = (const float*)d_in[0];   // [4,2048,4096] f32
    const int*   wq     = (const int*)  d_in[1];   // [16384,4096] int32 idx
    const float* absmax = (const float*)d_in[2];   // [16384]
    const float* code   = (const float*)d_in[3];   // [256]
    const float* bias   = (const float*)d_in[4];   // [16384]
    float* out = (float*)d_out;                    // [4,2048,16384] f32

    unsigned short* wb = (unsigned short*)d_ws;                    // W bf16 134 MB
    unsigned short* xb = wb + (size_t)N_TOTAL * K_TOTAL;           // x bf16  67 MB

    dequant_w_kernel<<<2048, 256, 0, stream>>>(wq, absmax, code, wb);
    cvt_x_kernel   <<<2048, 256, 0, stream>>>(x, xb);

    dim3 grid((M_TOTAL / BM) * (N_TOTAL / BN));    // 32*128 = 4096 blocks
    gemm_tb_kernel<<<grid, 256, 0, stream>>>(xb, wb, bias, out);
}

// Round 23
// 1077.062 us; speedup vs baseline: 1.2116x; 1.2116x over previous
//
#include <hip/hip_runtime.h>
#include <hip/hip_bf16.h>
#include <stdint.h>

#define M_TOTAL 8192      // BATCH*SEQ
#define N_TOTAL 16384     // OUT_FEATURES
#define K_TOTAL 4096      // IN_FEATURES (== BLOCKSIZE -> absmax is per output row)

#define BM 256
#define BN 256
#define BK 64
#define NKT (K_TOTAL / BK)   // 64 K-tiles

using f32x4  = __attribute__((ext_vector_type(4))) float;
using bf16x8 = __attribute__((ext_vector_type(8))) short;

#define UNROLL _Pragma("unroll")

__device__ __forceinline__ unsigned short f2bf(float f) {
    union { float f; unsigned u; } v; v.f = f;
    unsigned r = v.u + 0x7fffu + ((v.u >> 16) & 1u);   // RNE
    return (unsigned short)(r >> 16);
}

__device__ __forceinline__ void gload_lds16(const void* g, void* l) {
    __builtin_amdgcn_global_load_lds(
        (const __attribute__((address_space(1))) unsigned int*)g,
        (__attribute__((address_space(3))) unsigned int*)l,
        16, 0, 0);
}

// ---------------- dequant W: wb[o*K+i] = bf16(code[q[o*K+i]] * absmax[o]) ----------
__global__ void dequant_w_kernel(const int* __restrict__ q,
                                 const float* __restrict__ am,
                                 const float* __restrict__ code,
                                 unsigned short* __restrict__ wb) {
    __shared__ float lc[256];
    if (threadIdx.x < 256) lc[threadIdx.x] = code[threadIdx.x];
    __syncthreads();
    const int total = (N_TOTAL / 4) * K_TOTAL;   // 16,777,216 int4 groups
    const int stride = gridDim.x * blockDim.x;
    for (int i = blockIdx.x * blockDim.x + threadIdx.x; i < total; i += stride) {
        int4 v = reinterpret_cast<const int4*>(q)[i];
        float a = am[i >> 10];                   // one quant block == one weight row
        ushort4 o;
        o.x = f2bf(lc[v.x & 255] * a);
        o.y = f2bf(lc[v.y & 255] * a);
        o.z = f2bf(lc[v.z & 255] * a);
        o.w = f2bf(lc[v.w & 255] * a);
        reinterpret_cast<ushort4*>(wb)[i] = o;
    }
}

// ---------------- convert x fp32 -> bf16 ----------------
__global__ void cvt_x_kernel(const float* __restrict__ x,
                             unsigned short* __restrict__ xb) {
    const int total = (M_TOTAL * K_TOTAL) / 4;
    const int stride = gridDim.x * blockDim.x;
    for (int i = blockIdx.x * blockDim.x + threadIdx.x; i < total; i += stride) {
        float4 v = reinterpret_cast<const float4*>(x)[i];
        ushort4 o;
        o.x = f2bf(v.x); o.y = f2bf(v.y); o.z = f2bf(v.z); o.w = f2bf(v.w);
        reinterpret_cast<ushort4*>(xb)[i] = o;
    }
}

// ---- GEMM 256x256x64: 4 phases/K-tile, stage t+2, ONE barrier/phase (no MID drain)
// LDS swizzle (verified 0 conflicts): logical k-slot = ks*4+(lane>>4),
// physical = logical ^ (lane&7); linear gload_lds dest + pre-swizzled source.
#define LOAD_A(BUFI, MH)                                                          \
    UNROLL for (int mf = 0; mf < 4; ++mf)                                         \
        UNROLL for (int ks = 0; ks < 2; ++ks)                                     \
            a_r[mf][ks] = *reinterpret_cast<const bf16x8*>(                       \
                &sA[BUFI][((MH)*128 + arow_base + mf*16)*BK +                     \
                          (((ks*4 + rslot_hi) ^ rslot_xor)*8)]);

#define LOAD_B(DST, BUFI, NH)                                                     \
    UNROLL for (int nf = 0; nf < 2; ++nf)                                         \
        UNROLL for (int ks = 0; ks < 2; ++ks)                                     \
            DST[nf][ks] = *reinterpret_cast<const bf16x8*>(                       \
                &sB[BUFI][((NH)*128 + brow_base + nf*16)*BK +                     \
                          (((ks*4 + rslot_hi) ^ rslot_xor)*8)]);

#define MFMA_Q(MH, NH, BR)                                                        \
    UNROLL for (int mf = 0; mf < 4; ++mf)                                         \
        UNROLL for (int nf = 0; nf < 2; ++nf) {                                   \
            acc[MH][mf][NH][nf] = __builtin_amdgcn_mfma_f32_16x16x32_bf16(        \
                a_r[mf][0], BR[nf][0], acc[MH][mf][NH][nf], 0, 0, 0);             \
            acc[MH][mf][NH][nf] = __builtin_amdgcn_mfma_f32_16x16x32_bf16(        \
                a_r[mf][1], BR[nf][1], acc[MH][mf][NH][nf], 0, 0, 0);             \
        }

// phase-end: own-wave LDS drain (reads already consumed by MFMA -> cheap),
// then barrier (publishes "all waves' reads of this phase complete" -> staging
// over those halves is WAR-safe next phase), then compiler fence (no hoisting).
#define PH_BAR()                                                                  \
    asm volatile("s_waitcnt lgkmcnt(0)" ::: "memory");                            \
    __builtin_amdgcn_s_barrier();                                                 \
    asm volatile("" ::: "memory");

// One K-tile = 4 compiler-scheduled phases. Reads/stages/MFMA free-run inside a
// phase (fine-grained lgkmcnt per MFMA = m97 mechanism); one barrier per phase.
// WAR: Ah0,Bh0 read ph1 -> staged ph2; Bh1 read ph2 -> staged ph3; Ah1 read
// ph3 -> staged ph4. b0_r/a_r register-resident for ph4's q10 (no ph4 reads).
#define TILE_CORE(BUF, STG, TS)                                                   \
    /* ph1: read A0+B0 (12); q00 */                                               \
    LOAD_A(BUF, 0); LOAD_B(b0_r, BUF, 0);                                         \
    __builtin_amdgcn_s_setprio(1); MFMA_Q(0, 0, b0_r);                            \
    __builtin_amdgcn_s_setprio(0);                                                \
    PH_BAR();                                                                     \
    /* ph2: read B1 (4); stage Ah0,Bh0(TS); q01 */                                \
    LOAD_B(b1_r, BUF, 1);                                                         \
    if (STG) { stA(0,0,TS,BUF); stA(0,1,TS,BUF);                                  \
               stB(0,0,TS,BUF); stB(0,1,TS,BUF); }                                \
    __builtin_amdgcn_s_setprio(1); MFMA_Q(0, 1, b1_r);                            \
    __builtin_amdgcn_s_setprio(0);                                                \
    PH_BAR();                                                                     \
    /* ph3: read A1 (8); stage Bh1(TS); q11 */                                    \
    LOAD_A(BUF, 1);                                                               \
    if (STG) { stB(1,0,TS,BUF); stB(1,1,TS,BUF); }                                \
    __builtin_amdgcn_s_setprio(1); MFMA_Q(1, 1, b1_r);                            \
    __builtin_amdgcn_s_setprio(0);                                                \
    PH_BAR();                                                                     \
    /* ph4: no reads; stage Ah1(TS); q10 (a_r, b0_r resident) */                  \
    if (STG) { stA(1,0,TS,BUF); stA(1,1,TS,BUF); }                                \
    __builtin_amdgcn_s_setprio(1); MFMA_Q(1, 0, b0_r);                            \
    __builtin_amdgcn_s_setprio(0);

// tile-end gate: wait tile t+1's stages (issued 4-7 phases ago -> free), leave
// tile t+2's 8 in flight; barrier publishes; fence stops read hoisting.
#define GATE8()                                                                   \
    asm volatile("s_waitcnt vmcnt(8)" ::: "memory");                              \
    __builtin_amdgcn_s_barrier();                                                 \
    asm volatile("" ::: "memory");

#define GATE0()                                                                   \
    asm volatile("s_waitcnt vmcnt(0)" ::: "memory");                              \
    __builtin_amdgcn_s_barrier();                                                 \
    asm volatile("" ::: "memory");

__global__ __launch_bounds__(512, 2) void gemm_nb_kernel(
        const unsigned short* __restrict__ A,   // [M][K] bf16
        const unsigned short* __restrict__ B,   // [N][K] bf16
        const float* __restrict__ bias,         // [N]
        float* __restrict__ C) {                // [M][N] f32
    __shared__ __align__(16) unsigned short sA[2][BM * BK];   // 2 x 32 KB
    __shared__ __align__(16) unsigned short sB[2][BN * BK];   // 2 x 32 KB

    // XCD swizzle (nwg = 2048, % 8 == 0 -> bijective)
    const int nwg = gridDim.x;
    const int bid = blockIdx.x;
    const int wg  = (bid & 7) * (nwg >> 3) + (bid >> 3);
    const int nbn = N_TOTAL / BN;            // 64
    const int brow = (wg / nbn) * BM;
    const int bcol = (wg % nbn) * BN;

    const int tid  = threadIdx.x;
    const int wid  = tid >> 6;               // 0..7
    const int lane = tid & 63;
    const int wm   = wid >> 2;               // 0..1  (M-waves)
    const int wn   = wid & 3;                // 0..3  (N-waves)

    // staging: linear LDS dest + pre-swizzled global source (rule #21)
    const int srow = wid * 8 + (lane >> 3);
    const int scol = ((lane & 7) ^ (lane >> 3)) * 8;
    const unsigned short* Asrc = A + (long long)(brow + srow) * K_TOTAL + scol;
    const unsigned short* Bsrc = B + (long long)(bcol + srow) * K_TOTAL + scol;

    auto stA = [&](int h, int j, int kt, int b) {
        gload_lds16(Asrc + (long long)(h*128 + j*64) * K_TOTAL + kt*BK,
                    &sA[b][(h*128 + j*64)*BK + wid*512]);
    };
    auto stB = [&](int h, int j, int kt, int b) {
        gload_lds16(Bsrc + (long long)(h*128 + j*64) * K_TOTAL + kt*BK,
                    &sB[b][(h*128 + j*64)*BK + wid*512]);
    };

    // ds-read constants (swizzled read side)
    const int arow_base = wm * 64 + (lane & 15);   // + mh*128 + mf*16
    const int brow_base = wn * 32 + (lane & 15);   // + nh*128 + nf*16
    const int rslot_hi  = lane >> 4;
    const int rslot_xor = lane & 7;

    f32x4 acc[2][4][2][2];
    UNROLL for (int mh = 0; mh < 2; ++mh)
        UNROLL for (int mf = 0; mf < 4; ++mf)
            UNROLL for (int nh = 0; nh < 2; ++nh)
                UNROLL for (int nf = 0; nf < 2; ++nf)
                    acc[mh][mf][nh][nf] = (f32x4){0.f, 0.f, 0.f, 0.f};

    bf16x8 a_r[4][2];                 // current A half (A0 in ph1-2, A1 in ph3-4)
    bf16x8 b0_r[2][2], b1_r[2][2];    // B half0 (tile-resident) / half1

    // ---- prologue: tile0 -> buf0 (8 issues), tile1 -> buf1 (8 issues) ----
    stA(0,0,0,0); stA(0,1,0,0); stA(1,0,0,0); stA(1,1,0,0);
    stB(0,0,0,0); stB(0,1,0,0); stB(1,0,0,0); stB(1,1,0,0);
    stA(0,0,1,1); stA(0,1,1,1); stA(1,0,1,1); stA(1,1,1,1);
    stB(0,0,1,1); stB(0,1,1,1); stB(1,0,1,1); stB(1,1,1,1);
    asm volatile("s_waitcnt vmcnt(8)" ::: "memory");   // tile0 landed
    __builtin_amdgcn_s_barrier();
    asm volatile("" ::: "memory");

    // ---- main loop: t = 0..61, staging t+2 into the buffer being read ----
    for (int it = 0; it < NKT/2 - 1; ++it) {          // 31 iterations
        const int t0 = 2*it;
        TILE_CORE(0, 1, t0 + 2)
        GATE8();
        TILE_CORE(1, 1, t0 + 3)
        GATE8();
    }
    // t = 62: no staging; drain everything (tile 63's stages)
    TILE_CORE(0, 0, 0)
    GATE0();
    // t = 63: no staging, nothing outstanding
    TILE_CORE(1, 0, 0)

    // ---- epilogue: C/D layout col = lane&15, row = (lane>>4)*4 + r ----
    const int crow0 = (lane >> 4) * 4;
    const int ccol  = lane & 15;
    UNROLL for (int mh = 0; mh < 2; ++mh)
        UNROLL for (int mf = 0; mf < 4; ++mf) {
            const long long row0 = (long long)brow + mh*128 + wm*64 + mf*16 + crow0;
            UNROLL for (int nh = 0; nh < 2; ++nh)
                UNROLL for (int nf = 0; nf < 2; ++nf) {
                    const int col = bcol + nh*128 + wn*32 + nf*16 + ccol;
                    const float bv = bias[col];
                    UNROLL for (int r = 0; r < 4; ++r)
                        C[(row0 + r) * N_TOTAL + col] = acc[mh][mf][nh][nf][r] + bv;
                }
        }
}

extern "C" void kernel_launch(void* const* d_in, const int* in_sizes, int n_in,
                              void* d_out, int out_size, void* d_ws, size_t ws_size,
                              hipStream_t stream) {
    const float* x      = (const float*)d_in[0];   // [4,2048,4096] f32
    const int*   wq     = (const int*)  d_in[1];   // [16384,4096] int32 idx
    const float* absmax = (const float*)d_in[2];   // [16384]
    const float* code   = (const float*)d_in[3];   // [256]
    const float* bias   = (const float*)d_in[4];   // [16384]
    float* out = (float*)d_out;                    // [4,2048,16384] f32

    unsigned short* wb = (unsigned short*)d_ws;                    // W bf16 134 MB
    unsigned short* xb = wb + (size_t)N_TOTAL * K_TOTAL;           // x bf16  67 MB

    dequant_w_kernel<<<2048, 256, 0, stream>>>(wq, absmax, code, wb);
    cvt_x_kernel   <<<2048, 256, 0, stream>>>(x, xb);

    dim3 grid((M_TOTAL / BM) * (N_TOTAL / BN));    // 32*64 = 2048 blocks
    gemm_nb_kernel<<<grid, 512, 0, stream>>>(xb, wb, bias, out);
}

// Round 24
// 1074.842 us; speedup vs baseline: 1.2141x; 1.0021x over previous
//
#include <hip/hip_runtime.h>
#include <hip/hip_bf16.h>
#include <stdint.h>

#define M_TOTAL 8192      // BATCH*SEQ
#define N_TOTAL 16384     // OUT_FEATURES
#define K_TOTAL 4096      // IN_FEATURES (== BLOCKSIZE -> absmax is per output row)

#define BM 256
#define BN 256
#define BK 64
#define NKT (K_TOTAL / BK)   // 64 K-tiles

using f32x4  = __attribute__((ext_vector_type(4))) float;
using bf16x8 = __attribute__((ext_vector_type(8))) short;

#define UNROLL _Pragma("unroll")

__device__ __forceinline__ unsigned short f2bf(float f) {
    union { float f; unsigned u; } v; v.f = f;
    unsigned r = v.u + 0x7fffu + ((v.u >> 16) & 1u);   // RNE
    return (unsigned short)(r >> 16);
}

__device__ __forceinline__ void gload_lds16(const void* g, void* l) {
    __builtin_amdgcn_global_load_lds(
        (const __attribute__((address_space(1))) unsigned int*)g,
        (__attribute__((address_space(3))) unsigned int*)l,
        16, 0, 0);
}

// ---------------- dequant W: wb[o*K+i] = bf16(code[q[o*K+i]] * absmax[o]) ----------
__global__ void dequant_w_kernel(const int* __restrict__ q,
                                 const float* __restrict__ am,
                                 const float* __restrict__ code,
                                 unsigned short* __restrict__ wb) {
    __shared__ float lc[256];
    if (threadIdx.x < 256) lc[threadIdx.x] = code[threadIdx.x];
    __syncthreads();
    const int total = (N_TOTAL / 4) * K_TOTAL;   // 16,777,216 int4 groups
    const int stride = gridDim.x * blockDim.x;
    for (int i = blockIdx.x * blockDim.x + threadIdx.x; i < total; i += stride) {
        int4 v = reinterpret_cast<const int4*>(q)[i];
        float a = am[i >> 10];                   // one quant block == one weight row
        ushort4 o;
        o.x = f2bf(lc[v.x & 255] * a);
        o.y = f2bf(lc[v.y & 255] * a);
        o.z = f2bf(lc[v.z & 255] * a);
        o.w = f2bf(lc[v.w & 255] * a);
        reinterpret_cast<ushort4*>(wb)[i] = o;
    }
}

// ---------------- convert x fp32 -> bf16 ----------------
__global__ void cvt_x_kernel(const float* __restrict__ x,
                             unsigned short* __restrict__ xb) {
    const int total = (M_TOTAL * K_TOTAL) / 4;
    const int stride = gridDim.x * blockDim.x;
    for (int i = blockIdx.x * blockDim.x + threadIdx.x; i < total; i += stride) {
        float4 v = reinterpret_cast<const float4*>(x)[i];
        ushort4 o;
        o.x = f2bf(v.x); o.y = f2bf(v.y); o.z = f2bf(v.z); o.w = f2bf(v.w);
        reinterpret_cast<ushort4*>(xb)[i] = o;
    }
}

// ---- GEMM 256x256x64: 4 phases/K-tile, stage t+2, ONE barrier/phase (no MID drain)
// Session optimum, verified x3 (r16/r21/r23): 1077-1081 us total, MfmaUtil 50%,
// 0 bank conflicts. Structural constraint: 224 regs/wave -> 2 waves/SIMD in one
// barrier domain; the residual vs MFMA floor is simultaneous-stall lockstep,
// bracketed by 11 falsified structural variants (see session journal r6-r22).
// LDS swizzle (verified 0 conflicts): logical k-slot = ks*4+(lane>>4),
// physical = logical ^ (lane&7); linear gload_lds dest + pre-swizzled source.
#define LOAD_A(BUFI, MH)                                                          \
    UNROLL for (int mf = 0; mf < 4; ++mf)                                         \
        UNROLL for (int ks = 0; ks < 2; ++ks)                                     \
            a_r[mf][ks] = *reinterpret_cast<const bf16x8*>(                       \
                &sA[BUFI][((MH)*128 + arow_base + mf*16)*BK +                     \
                          (((ks*4 + rslot_hi) ^ rslot_xor)*8)]);

#define LOAD_B(DST, BUFI, NH)                                                     \
    UNROLL for (int nf = 0; nf < 2; ++nf)                                         \
        UNROLL for (int ks = 0; ks < 2; ++ks)                                     \
            DST[nf][ks] = *reinterpret_cast<const bf16x8*>(                       \
                &sB[BUFI][((NH)*128 + brow_base + nf*16)*BK +                     \
                          (((ks*4 + rslot_hi) ^ rslot_xor)*8)]);

#define MFMA_Q(MH, NH, BR)                                                        \
    UNROLL for (int mf = 0; mf < 4; ++mf)                                         \
        UNROLL for (int nf = 0; nf < 2; ++nf) {                                   \
            acc[MH][mf][NH][nf] = __builtin_amdgcn_mfma_f32_16x16x32_bf16(        \
                a_r[mf][0], BR[nf][0], acc[MH][mf][NH][nf], 0, 0, 0);             \
            acc[MH][mf][NH][nf] = __builtin_amdgcn_mfma_f32_16x16x32_bf16(        \
                a_r[mf][1], BR[nf][1], acc[MH][mf][NH][nf], 0, 0, 0);             \
        }

// phase-end: own-wave LDS drain (reads already consumed by MFMA -> cheap),
// then barrier (publishes "all waves' reads of this phase complete" -> staging
// over those halves is WAR-safe next phase), then compiler fence (no hoisting).
#define PH_BAR()                                                                  \
    asm volatile("s_waitcnt lgkmcnt(0)" ::: "memory");                            \
    __builtin_amdgcn_s_barrier();                                                 \
    asm volatile("" ::: "memory");

// One K-tile = 4 compiler-scheduled phases. Reads/stages/MFMA free-run inside a
// phase (fine-grained lgkmcnt per MFMA = m97 mechanism); one barrier per phase.
// WAR: Ah0,Bh0 read ph1 -> staged ph2; Bh1 read ph2 -> staged ph3; Ah1 read
// ph3 -> staged ph4. b0_r/a_r register-resident for ph4's q10 (no ph4 reads).
#define TILE_CORE(BUF, STG, TS)                                                   \
    /* ph1: read A0+B0 (12); q00 */                                               \
    LOAD_A(BUF, 0); LOAD_B(b0_r, BUF, 0);                                         \
    __builtin_amdgcn_s_setprio(1); MFMA_Q(0, 0, b0_r);                            \
    __builtin_amdgcn_s_setprio(0);                                                \
    PH_BAR();                                                                     \
    /* ph2: read B1 (4); stage Ah0,Bh0(TS); q01 */                                \
    LOAD_B(b1_r, BUF, 1);                                                         \
    if (STG) { stA(0,0,TS,BUF); stA(0,1,TS,BUF);                                  \
               stB(0,0,TS,BUF); stB(0,1,TS,BUF); }                                \
    __builtin_amdgcn_s_setprio(1); MFMA_Q(0, 1, b1_r);                            \
    __builtin_amdgcn_s_setprio(0);                                                \
    PH_BAR();                                                                     \
    /* ph3: read A1 (8); stage Bh1(TS); q11 */                                    \
    LOAD_A(BUF, 1);                                                               \
    if (STG) { stB(1,0,TS,BUF); stB(1,1,TS,BUF); }                                \
    __builtin_amdgcn_s_setprio(1); MFMA_Q(1, 1, b1_r);                            \
    __builtin_amdgcn_s_setprio(0);                                                \
    PH_BAR();                                                                     \
    /* ph4: no reads; stage Ah1(TS); q10 (a_r, b0_r resident) */                  \
    if (STG) { stA(1,0,TS,BUF); stA(1,1,TS,BUF); }                                \
    __builtin_amdgcn_s_setprio(1); MFMA_Q(1, 0, b0_r);                            \
    __builtin_amdgcn_s_setprio(0);

// tile-end gate: wait tile t+1's stages (issued 4-7 phases ago -> free), leave
// tile t+2's 8 in flight; barrier publishes; fence stops read hoisting.
#define GATE8()                                                                   \
    asm volatile("s_waitcnt vmcnt(8)" ::: "memory");                              \
    __builtin_amdgcn_s_barrier();                                                 \
    asm volatile("" ::: "memory");

#define GATE0()                                                                   \
    asm volatile("s_waitcnt vmcnt(0)" ::: "memory");                              \
    __builtin_amdgcn_s_barrier();                                                 \
    asm volatile("" ::: "memory");

__global__ __launch_bounds__(512, 2) void gemm_nb_kernel(
        const unsigned short* __restrict__ A,   // [M][K] bf16
        const unsigned short* __restrict__ B,   // [N][K] bf16
        const float* __restrict__ bias,         // [N]
        float* __restrict__ C) {                // [M][N] f32
    __shared__ __align__(16) unsigned short sA[2][BM * BK];   // 2 x 32 KB
    __shared__ __align__(16) unsigned short sB[2][BN * BK];   // 2 x 32 KB

    // XCD swizzle (nwg = 2048, % 8 == 0 -> bijective)
    const int nwg = gridDim.x;
    const int bid = blockIdx.x;
    const int wg  = (bid & 7) * (nwg >> 3) + (bid >> 3);
    const int nbn = N_TOTAL / BN;            // 64
    const int brow = (wg / nbn) * BM;
    const int bcol = (wg % nbn) * BN;

    const int tid  = threadIdx.x;
    const int wid  = tid >> 6;               // 0..7
    const int lane = tid & 63;
    const int wm   = wid >> 2;               // 0..1  (M-waves)
    const int wn   = wid & 3;                // 0..3  (N-waves)

    // staging: linear LDS dest + pre-swizzled global source (rule #21)
    const int srow = wid * 8 + (lane >> 3);
    const int scol = ((lane & 7) ^ (lane >> 3)) * 8;
    const unsigned short* Asrc = A + (long long)(brow + srow) * K_TOTAL + scol;
    const unsigned short* Bsrc = B + (long long)(bcol + srow) * K_TOTAL + scol;

    auto stA = [&](int h, int j, int kt, int b) {
        gload_lds16(Asrc + (long long)(h*128 + j*64) * K_TOTAL + kt*BK,
                    &sA[b][(h*128 + j*64)*BK + wid*512]);
    };
    auto stB = [&](int h, int j, int kt, int b) {
        gload_lds16(Bsrc + (long long)(h*128 + j*64) * K_TOTAL + kt*BK,
                    &sB[b][(h*128 + j*64)*BK + wid*512]);
    };

    // ds-read constants (swizzled read side)
    const int arow_base = wm * 64 + (lane & 15);   // + mh*128 + mf*16
    const int brow_base = wn * 32 + (lane & 15);   // + nh*128 + nf*16
    const int rslot_hi  = lane >> 4;
    const int rslot_xor = lane & 7;

    f32x4 acc[2][4][2][2];
    UNROLL for (int mh = 0; mh < 2; ++mh)
        UNROLL for (int mf = 0; mf < 4; ++mf)
            UNROLL for (int nh = 0; nh < 2; ++nh)
                UNROLL for (int nf = 0; nf < 2; ++nf)
                    acc[mh][mf][nh][nf] = (f32x4){0.f, 0.f, 0.f, 0.f};

    bf16x8 a_r[4][2];                 // current A half (A0 in ph1-2, A1 in ph3-4)
    bf16x8 b0_r[2][2], b1_r[2][2];    // B half0 (tile-resident) / half1

    // ---- prologue: tile0 -> buf0 (8 issues), tile1 -> buf1 (8 issues) ----
    stA(0,0,0,0); stA(0,1,0,0); stA(1,0,0,0); stA(1,1,0,0);
    stB(0,0,0,0); stB(0,1,0,0); stB(1,0,0,0); stB(1,1,0,0);
    stA(0,0,1,1); stA(0,1,1,1); stA(1,0,1,1); stA(1,1,1,1);
    stB(0,0,1,1); stB(0,1,1,1); stB(1,0,1,1); stB(1,1,1,1);
    asm volatile("s_waitcnt vmcnt(8)" ::: "memory");   // tile0 landed
    __builtin_amdgcn_s_barrier();
    asm volatile("" ::: "memory");

    // ---- main loop: t = 0..61, staging t+2 into the buffer being read ----
    for (int it = 0; it < NKT/2 - 1; ++it) {          // 31 iterations
        const int t0 = 2*it;
        TILE_CORE(0, 1, t0 + 2)
        GATE8();
        TILE_CORE(1, 1, t0 + 3)
        GATE8();
    }
    // t = 62: no staging; drain everything (tile 63's stages)
    TILE_CORE(0, 0, 0)
    GATE0();
    // t = 63: no staging, nothing outstanding
    TILE_CORE(1, 0, 0)

    // ---- epilogue: C/D layout col = lane&15, row = (lane>>4)*4 + r ----
    const int crow0 = (lane >> 4) * 4;
    const int ccol  = lane & 15;
    UNROLL for (int mh = 0; mh < 2; ++mh)
        UNROLL for (int mf = 0; mf < 4; ++mf) {
            const long long row0 = (long long)brow + mh*128 + wm*64 + mf*16 + crow0;
            UNROLL for (int nh = 0; nh < 2; ++nh)
                UNROLL for (int nf = 0; nf < 2; ++nf) {
                    const int col = bcol + nh*128 + wn*32 + nf*16 + ccol;
                    const float bv = bias[col];
                    UNROLL for (int r = 0; r < 4; ++r)
                        C[(row0 + r) * N_TOTAL + col] = acc[mh][mf][nh][nf][r] + bv;
                }
        }
}

extern "C" void kernel_launch(void* const* d_in, const int* in_sizes, int n_in,
                              void* d_out, int out_size, void* d_ws, size_t ws_size,
                              hipStream_t stream) {
    const float* x      = (const float*)d_in[0];   // [4,2048,4096] f32
    const int*   wq     = (const int*)  d_in[1];   // [16384,4096] int32 idx
    const float* absmax = (const float*)d_in[2];   // [16384]
    const float* code   = (const float*)d_in[3];   // [256]
    const float* bias   = (const float*)d_in[4];   // [16384]
    float* out = (float*)d_out;                    // [4,2048,16384] f32

    unsigned short* wb = (unsigned short*)d_ws;                    // W bf16 134 MB
    unsigned short* xb = wb + (size_t)N_TOTAL * K_TOTAL;           // x bf16  67 MB

    dequant_w_kernel<<<2048, 256, 0, stream>>>(wq, absmax, code, wb);
    cvt_x_kernel   <<<2048, 256, 0, stream>>>(x, xb);

    dim3 grid((M_TOTAL / BM) * (N_TOTAL / BN));    // 32*64 = 2048 blocks
    gemm_nb_kernel<<<grid, 512, 0, stream>>>(xb, wb, bias, out);
}